// Round 3
// baseline (470.912 us; speedup 1.0000x reference)
//
#include <hip/hip_runtime.h>
#include <stdint.h>

typedef unsigned int u32;
typedef unsigned long long u64;

#define BB 16
#define NN 25200
#define ROWLEN 85
#define KCAND 1024
#define MAXDET 1000
#define CONF_T 0.25f
#define IOU_T 0.45f
#define MAX_WH 4096.0f
#define KBASE 0xBE800000u    // f2key(0.25f); valid keys in (KBASE, KBASE+0x1000000)
#define NBLK 394             // ceil(25200/64) blocks per image in k_score

__device__ __forceinline__ u32 f2key(float f) {
  u32 u = __float_as_uint(f);
  return (u & 0x80000000u) ? ~u : (u | 0x80000000u);
}
__device__ __forceinline__ float key2f(u32 k) {
  u32 u = (k & 0x80000000u) ? (k & 0x7FFFFFFFu) : ~k;
  return __uint_as_float(u);
}

// ---------------- K1: per-thread row reduce from LDS (pure streaming) ---------------
// Unrolled float4 staging (21 loads issued back-to-back -> latency overlapped; the
// dynamic-loop variant serialized the loads and cost ~20 us in round 1). Tail block
// (48 rows) takes the slow path -- only 16 of 6304 blocks. gh histogram machinery
// removed (round-2 post-mortem: it cost ~+8 us net; baseline per-wave atomics in
// k_select pass-1 were never a bottleneck). Writes the 24-bit key (0 = invalid).
__global__ __launch_bounds__(64) void k_score(const float* __restrict__ pred,
                                              u32* __restrict__ keys,
                                              int* __restrict__ clsArr) {
  __shared__ float sh[64 * ROWLEN];          // 21760 B -> 7 blocks/CU
  const int t = threadIdx.x;
  const int bi = blockIdx.x;                 // 0..393 within image
  const int img = blockIdx.y;                // 0..15
  const int r0 = bi * 64;
  const float4* src = (const float4*)(pred + ((size_t)img * NN + r0) * ROWLEN);
  float4* dst = (float4*)sh;
  if (r0 + 64 <= NN) {
    #pragma unroll
    for (int i = 0; i < 21; ++i) dst[t + 64 * i] = src[t + 64 * i];
    if (t < 16) dst[t + 64 * 21] = src[t + 64 * 21];
  } else {
    const int nf4 = (NN - r0) * ROWLEN / 4;  // 48*85/4 = 1020
    for (int i = t; i < nf4; i += 64) dst[i] = src[i];
  }
  __syncthreads();
  const int nrows = (r0 + 64 <= NN) ? 64 : (NN - r0);
  if (t < nrows) {
    const float* row = sh + t * ROWLEN;
    float obj = row[4];
    float v0 = -INFINITY, v1 = -INFINITY, v2 = -INFINITY, v3 = -INFINITY;
    int j0 = 0, j1 = 20, j2 = 40, j3 = 60;
    #pragma unroll
    for (int c = 0; c < 20; ++c) {
      float s0 = obj * row[5 + c];
      float s1 = obj * row[25 + c];
      float s2 = obj * row[45 + c];
      float s3 = obj * row[65 + c];
      if (s0 > v0) { v0 = s0; j0 = c; }
      if (s1 > v1) { v1 = s1; j1 = 20 + c; }
      if (s2 > v2) { v2 = s2; j2 = 40 + c; }
      if (s3 > v3) { v3 = s3; j3 = 60 + c; }
    }
    float v = v0; int j = j0;
    if (v1 > v) { v = v1; j = j1; }
    if (v2 > v) { v = v2; j = j2; }
    if (v3 > v) { v = v3; j = j3; }
    u32 key = (v > CONF_T) ? (f2key(v) - KBASE) : 0u;   // 24-bit, >= 1 when valid
    size_t r = (size_t)img * NN + r0 + t;
    keys[r] = key;
    clsArr[r] = j;
  }
}

// ---- bitonic helper ----
__device__ __forceinline__ void bt_apply(u64& e, u64 p, int m, int j, int k) {
  bool lower = ((m & j) == 0);
  bool dir = ((m & k) == 0);
  bool takeMax = (lower == dir);
  u64 mx = e > p ? e : p;
  u64 mn = e > p ? p : e;
  e = takeMax ? mx : mn;
}

// -------- K2: top-1024 via 24-bit rank radix select (3 passes) + hybrid bitonic -----
// Pass 1: baseline per-wave hist[16][257] LDS atomics (verified, ~1 us). Passes 2/3:
// single hist1 (few matching elements). Sort: fast path when cnt<=1024 (no ties at
// threshold -> e1 region all zero -> sort e0 only, skip k=2048 merge).
__global__ __launch_bounds__(1024, 4) void k_select(const float* __restrict__ pred,
                                                    const u32* __restrict__ keys,
                                                    const int* __restrict__ clsArr,
                                                    float* __restrict__ candScore,
                                                    float* __restrict__ candBox,
                                                    int* __restrict__ candCls) {
  __shared__ u32 hist[16][257];
  __shared__ u32 hist1[257];
  __shared__ u64 buf[2048];
  __shared__ u32 sh_sel, sh_rem, sh_cnt;
  const int b = blockIdx.x;
  const int tid = threadIdx.x;
  const int lane = tid & 63;
  const int wv = tid >> 6;
  const u32* kk = keys + (size_t)b * NN;
  u32* histflat = (u32*)hist;

  u32 rr[25];
  #pragma unroll
  for (int it = 0; it < 25; ++it) {
    int n0 = tid + it * 1024;
    rr[it] = (n0 < NN) ? kk[n0] : 0u;
  }

  // ---- pass 1: top byte, per-wave private histograms (no contention) ----
  for (int i = tid; i < 16 * 257; i += 1024) histflat[i] = 0;
  if (tid == 0) sh_cnt = 0;
  __syncthreads();
  #pragma unroll
  for (int it = 0; it < 25; ++it) {
    u32 r = rr[it];
    if (r != 0u) atomicAdd(&hist[wv][r >> 16], 1u);
  }
  __syncthreads();
  if (wv == 0) {
    u32 c0 = 0, c1 = 0, c2 = 0, c3 = 0;
    #pragma unroll
    for (int w = 0; w < 16; ++w) {
      c0 += hist[w][4 * lane + 0];
      c1 += hist[w][4 * lane + 1];
      c2 += hist[w][4 * lane + 2];
      c3 += hist[w][4 * lane + 3];
    }
    u32 tl = c0 + c1 + c2 + c3;
    u32 incl = tl;
    #pragma unroll
    for (int off = 1; off <= 32; off <<= 1) {
      u32 o = __shfl_down(incl, off, 64);
      if (lane + off < 64) incl += o;
    }
    u32 S0 = incl;
    u32 S1 = S0 - c0;
    u32 S2 = S1 - c1;
    u32 S3 = S2 - c2;
    u32 S4 = S3 - c3;
    u32 rem = KCAND;
    if (S0 >= rem && S1 < rem) { sh_sel = 4 * lane + 0; sh_rem = rem - S1; }
    if (S1 >= rem && S2 < rem) { sh_sel = 4 * lane + 1; sh_rem = rem - S2; }
    if (S2 >= rem && S3 < rem) { sh_sel = 4 * lane + 2; sh_rem = rem - S3; }
    if (S3 >= rem && S4 < rem) { sh_sel = 4 * lane + 3; sh_rem = rem - S4; }
  }
  __syncthreads();
  u32 prefix = (sh_sel << 16);
  u32 remaining = sh_rem;
  u32 himask = 0xFF0000u;
  __syncthreads();

  // ---- passes 2 and 3: only prefix-matching elements (~bucket-sized) do atomics ----
  #pragma unroll
  for (int pass = 1; pass < 3; ++pass) {
    const int shift = 16 - 8 * pass;
    if (tid < 256) hist1[tid] = 0u;
    __syncthreads();
    #pragma unroll
    for (int it = 0; it < 25; ++it) {
      u32 r = rr[it];
      if (r != 0u && (r & himask) == prefix)
        atomicAdd(&hist1[(r >> shift) & 255], 1u);
    }
    __syncthreads();
    if (wv == 0) {
      const int j4 = lane << 2;
      u32 c0 = hist1[j4 + 0], c1 = hist1[j4 + 1], c2 = hist1[j4 + 2], c3 = hist1[j4 + 3];
      u32 tl = c0 + c1 + c2 + c3;
      u32 incl = tl;
      #pragma unroll
      for (int off = 1; off <= 32; off <<= 1) {
        u32 o = __shfl_down(incl, off, 64);
        if (lane + off < 64) incl += o;
      }
      u32 S0 = incl;
      u32 S1 = S0 - c0;
      u32 S2 = S1 - c1;
      u32 S3 = S2 - c2;
      u32 S4 = S3 - c3;
      u32 rem = remaining;
      if (S0 >= rem && S1 < rem) { sh_sel = 4 * lane + 0; sh_rem = rem - S1; }
      if (S1 >= rem && S2 < rem) { sh_sel = 4 * lane + 1; sh_rem = rem - S2; }
      if (S2 >= rem && S3 < rem) { sh_sel = 4 * lane + 2; sh_rem = rem - S3; }
      if (S3 >= rem && S4 < rem) { sh_sel = 4 * lane + 3; sh_rem = rem - S4; }
    }
    __syncthreads();
    prefix |= (sh_sel << shift);
    remaining = sh_rem;
    himask |= (0xFFu << shift);
    __syncthreads();
  }
  const u32 T = prefix;   // exact 24-bit threshold, T >= 1

  // ---- exact-threshold compaction (order irrelevant: full sort follows) ----
  #pragma unroll
  for (int it = 0; it < 25; ++it) {
    int n0 = tid + it * 1024;
    u32 r = rr[it];
    bool match = (r >= T);             // r==0 (invalid/OOB) never matches, T>=1
    u64 bal = __ballot(match);
    if (bal) {
      int leader = __ffsll((unsigned long long)bal) - 1;
      u32 base = 0;
      u32 cnt = (u32)__popcll(bal);
      if (lane == leader) base = atomicAdd(&sh_cnt, cnt);
      base = __shfl(base, leader, 64);
      if (match) {
        u32 pos = base + (u32)__popcll(bal & ((1ull << lane) - 1ull));
        if (pos < 2048) buf[pos] = ((u64)r << 32) | (u32)(~(u32)n0);
      }
    }
  }
  __syncthreads();
  u32 c = sh_cnt; if (c > 2048) c = 2048;
  for (int t = tid; t < 2048; t += 1024) if (t >= (int)c) buf[t] = 0;
  __syncthreads();

  u64 e0 = buf[tid];
  if (c <= 1024) {
    // fast path: no ties at threshold -> buf[1024..2047] all zero; sort e0 only,
    // final k=1024 stage yields full descending order (same dir convention).
    #pragma unroll
    for (int k = 2; k <= 64; k <<= 1) {
      #pragma unroll
      for (int j = k >> 1; j > 0; j >>= 1) {
        u64 p0 = __shfl_xor(e0, j, 64);
        bt_apply(e0, p0, tid, j, k);
      }
    }
    for (int k = 128; k <= 1024; k <<= 1) {
      for (int j = k >> 1; j >= 64; j >>= 1) {
        buf[tid] = e0;
        __syncthreads();
        u64 p0 = buf[tid ^ j];
        bt_apply(e0, p0, tid, j, k);
        __syncthreads();
      }
      #pragma unroll
      for (int j = 32; j > 0; j >>= 1) {
        u64 p0 = __shfl_xor(e0, j, 64);
        bt_apply(e0, p0, tid, j, k);
      }
    }
  } else {
    // full 2048 path (tie at threshold) -- verified baseline
    u64 e1 = buf[tid + 1024];
    #pragma unroll
    for (int k = 2; k <= 64; k <<= 1) {
      #pragma unroll
      for (int j = k >> 1; j > 0; j >>= 1) {
        u64 p0 = __shfl_xor(e0, j, 64);
        u64 p1 = __shfl_xor(e1, j, 64);
        bt_apply(e0, p0, tid, j, k);
        bt_apply(e1, p1, tid + 1024, j, k);
      }
    }
    for (int k = 128; k <= 2048; k <<= 1) {
      int jstart = k >> 1;
      if (k == 2048) {
        u64 mx = e0 > e1 ? e0 : e1;
        u64 mn = e0 > e1 ? e1 : e0;
        e0 = mx; e1 = mn;
        jstart = 512;
      }
      for (int j = jstart; j >= 64; j >>= 1) {
        buf[tid] = e0; buf[tid + 1024] = e1;
        __syncthreads();
        u64 p0 = buf[tid ^ j];
        u64 p1 = buf[(tid ^ j) + 1024];
        bt_apply(e0, p0, tid, j, k);
        bt_apply(e1, p1, tid + 1024, j, k);
        __syncthreads();
      }
      #pragma unroll
      for (int j = 32; j > 0; j >>= 1) {
        u64 p0 = __shfl_xor(e0, j, 64);
        u64 p1 = __shfl_xor(e1, j, 64);
        bt_apply(e0, p0, tid, j, k);
        bt_apply(e1, p1, tid + 1024, j, k);
      }
    }
  }
  {
    u64 e = e0;
    u32 r = (u32)(e >> 32);
    u32 idx = ~(u32)e;
    if (idx >= NN) idx = 0;
    float sc = key2f(r + KBASE);
    size_t g = (size_t)b * KCAND + tid;
    candScore[g] = sc;
    const float* p = pred + ((size_t)b * NN + idx) * ROWLEN;
    float cx = p[0], cy = p[1], w = p[2], h = p[3];
    float4 bx;
    bx.x = cx - 0.5f * w;
    bx.y = cy - 0.5f * h;
    bx.z = cx + 0.5f * w;
    bx.w = cy + 0.5f * h;
    ((float4*)candBox)[g] = bx;
    candCls[g] = clsArr[(size_t)b * NN + idx];
  }
}

// ---------------- K3a: ballot-transpose IoU, LOWER WEDGE ONLY (rc <= cc) -----------
// k_scan_out reads matT[b][c][row] only for row-chunk <= col-chunk, so skip the rest.
// Column boxes live in per-lane registers (loaded once); row boxes broadcast via
// uniform LDS reads; one __ballot produces each 64-bit matT word. Arithmetic is
// bit-identical to the verified kernel (fp contract off, same op order, exact f32 div).
__global__ __launch_bounds__(64) void k_iou(const float* __restrict__ candBox,
                                            const int* __restrict__ candCls,
                                            u64* __restrict__ matT) {
  #pragma clang fp contract(off)
  __shared__ float4 sb[64];
  __shared__ float sa[64];
  const int rc = blockIdx.x;       // row chunk
  const int cc = blockIdx.y;       // col chunk
  const int b  = blockIdx.z;
  if (rc > cc) return;
  const int lane = threadIdx.x;
  {
    int rrow = rc * 64 + lane;
    float4 bx = ((const float4*)candBox)[(size_t)b * KCAND + rrow];
    float off = (float)candCls[(size_t)b * KCAND + rrow] * MAX_WH;
    float x1 = bx.x + off, y1 = bx.y + off, x2 = bx.z + off, y2 = bx.w + off;
    float4 sbv; sbv.x = x1; sbv.y = y1; sbv.z = x2; sbv.w = y2;
    sb[lane] = sbv;
    sa[lane] = (x2 - x1) * (y2 - y1);
  }
  int col = cc * 64 + lane;
  float4 cb = ((const float4*)candBox)[(size_t)b * KCAND + col];
  float coff = (float)candCls[(size_t)b * KCAND + col] * MAX_WH;
  float cx1 = cb.x + coff, cy1 = cb.y + coff, cx2 = cb.z + coff, cy2 = cb.w + coff;
  float car = (cx2 - cx1) * (cy2 - cy1);
  __syncthreads();
  u64 myw = 0;
  for (int r = 0; r < 64; ++r) {
    float4 rb = sb[r];
    float ra = sa[r];
    float ix1 = fmaxf(rb.x, cx1);
    float iy1 = fmaxf(rb.y, cy1);
    float ix2 = fminf(rb.z, cx2);
    float iy2 = fminf(rb.w, cy2);
    float dx = fmaxf(ix2 - ix1, 0.0f);
    float dy = fmaxf(iy2 - iy1, 0.0f);
    float inter = dx * dy;
    float den = ra + car;
    den = den - inter;
    den = den + 1e-9f;
    float iou = inter / den;
    u64 bal = __ballot(iou > IOU_T);
    if (lane == r) myw = bal;
  }
  matT[(((size_t)b * 16 + cc) << 10) + rc * 64 + lane] = myw;
}

// -------- K3b (fused scan + output): ENTIRE lower triangle in wave-0 registers ------
#define TRIDX(c, cp) (((c) * ((c)-1)) / 2 + (cp))
__global__ __launch_bounds__(256, 1) void k_scan_out(const u64* __restrict__ matT,
                                                     const float* __restrict__ candScore,
                                                     const float* __restrict__ candBox,
                                                     const int* __restrict__ candCls,
                                                     float* __restrict__ out) {
  __shared__ u64 sKeep[16];
  const int b = blockIdx.x;
  const int tid = threadIdx.x;
  const u64* Mb = matT + ((size_t)b << 14);

  if (tid < 64) {
    const int lane = tid;
    u64 vw[16], dg[16], tri[120], kcw[16];
    #pragma unroll
    for (int w = 0; w < 16; ++w) {
      float sc = candScore[(size_t)b * KCAND + w * 64 + lane];
      vw[w] = __ballot(sc > 0.0f);
    }
    #pragma unroll
    for (int c = 0; c < 16; ++c)
      dg[c] = Mb[((size_t)c << 10) + c * 64 + lane];
    #pragma unroll
    for (int c = 1; c < 16; ++c) {
      #pragma unroll
      for (int cp = 0; cp < c; ++cp)
        tri[TRIDX(c, cp)] = Mb[((size_t)c << 10) + cp * 64 + lane];
    }

    #pragma unroll
    for (int c = 0; c < 16; ++c) {
      u64 acc = 0;
      #pragma unroll
      for (int cp = 0; cp < 15; ++cp) {
        if (cp < c) {
          if ((kcw[cp] >> lane) & 1ull) acc |= tri[TRIDX(c, cp)];
        }
      }
      #pragma unroll
      for (int st = 1; st < 64; st <<= 1) acc |= __shfl_xor(acc, st, 64);
      u64 d = dg[c];
      u64 s = acc;
      u64 kc = 0;
      u64 vc = vw[c];
      #pragma unroll
      for (int g = 0; g < 8; ++g) {
        u64 dgp[8];
        #pragma unroll
        for (int j = 0; j < 8; ++j) dgp[j] = __shfl(d, g * 8 + j, 64);
        #pragma unroll
        for (int j = 0; j < 8; ++j) {
          int i = g * 8 + j;
          bool ok = !((s >> i) & 1ull) && ((vc >> i) & 1ull);
          if (ok) { s |= dgp[j]; kc |= (1ull << i); }
        }
      }
      kcw[c] = kc;    // lane-uniform
    }
    if (lane < 16) sKeep[lane] = kcw[lane];
  }
  __syncthreads();

  int total = 0;
  #pragma unroll
  for (int w = 0; w < 16; ++w) total += __popcll(sKeep[w]);
  int kept_eff = total < MAXDET ? total : MAXDET;
  float* outb = out + (size_t)b * MAXDET * 6;
  #pragma unroll
  for (int rr2 = 0; rr2 < 4; ++rr2) {
    const int t = tid + rr2 * 256;
    u64 word = sKeep[t >> 6];
    int bit = (int)((word >> (t & 63)) & 1ull);
    int rank = 0;
    for (int w = 0; w < (t >> 6); ++w) rank += __popcll(sKeep[w]);
    rank += __popcll(word & ((1ull << (t & 63)) - 1ull));
    if (bit && rank < MAXDET) {
      size_t g = (size_t)b * KCAND + t;
      float4 bx = ((const float4*)candBox)[g];
      float sc = candScore[g];
      float cf = (float)candCls[g];
      float* o = outb + (size_t)rank * 6;
      o[0] = bx.x; o[1] = bx.y; o[2] = bx.z; o[3] = bx.w; o[4] = sc; o[5] = cf;
    }
    if (t < MAXDET && t >= kept_eff) {
      float* o = outb + (size_t)t * 6;
      o[0] = 0.f; o[1] = 0.f; o[2] = 0.f; o[3] = 0.f; o[4] = 0.f; o[5] = 0.f;
    }
  }
}

extern "C" void kernel_launch(void* const* d_in, const int* in_sizes, int n_in,
                              void* d_out, int out_size, void* d_ws, size_t ws_size,
                              hipStream_t stream) {
  const float* pred = (const float*)d_in[0];
  float* out = (float*)d_out;
  char* ws = (char*)d_ws;
  size_t o = 0;
  u32*   keysW     = (u32*)  (ws + o); o += (size_t)BB * NN * 4;
  int*   clsArr    = (int*)  (ws + o); o += (size_t)BB * NN * 4;
  float* candScore = (float*)(ws + o); o += (size_t)BB * KCAND * 4;
  float* candBox   = (float*)(ws + o); o += (size_t)BB * KCAND * 16;
  int*   candCls   = (int*)  (ws + o); o += (size_t)BB * KCAND * 4;
  o = (o + 255) & ~(size_t)255;
  u64*   matT      = (u64*)  (ws + o); o += (size_t)BB * KCAND * 16 * 8;   // 2 MB

  k_score<<<dim3(NBLK, BB), 64, 0, stream>>>(pred, keysW, clsArr);
  k_select<<<BB, 1024, 0, stream>>>(pred, keysW, clsArr, candScore, candBox, candCls);
  k_iou<<<dim3(16, 16, BB), 64, 0, stream>>>(candBox, candCls, matT);
  k_scan_out<<<BB, 256, 0, stream>>>(matT, candScore, candBox, candCls, out);
}

// Round 4
// 293.039 us; speedup vs baseline: 1.6070x; 1.6070x over previous
//
#include <hip/hip_runtime.h>
#include <stdint.h>

typedef unsigned int u32;
typedef unsigned long long u64;

#define BB 16
#define NN 25200
#define ROWLEN 85
#define KCAND 1024
#define MAXDET 1000
#define CONF_T 0.25f
#define IOU_T 0.45f
#define MAX_WH 4096.0f
#define KBASE 0xBE800000u    // f2key(0.25f); valid keys in (KBASE, KBASE+0x1000000)
#define NBLK 394             // ceil(25200/64) blocks per image in k_score

__device__ __forceinline__ u32 f2key(float f) {
  u32 u = __float_as_uint(f);
  return (u & 0x80000000u) ? ~u : (u | 0x80000000u);
}
__device__ __forceinline__ float key2f(u32 k) {
  u32 u = (k & 0x80000000u) ? (k & 0x7FFFFFFFu) : ~k;
  return __uint_as_float(u);
}

// ---------------- K1: per-thread row reduce from LDS (pure streaming) ---------------
// Unrolled float4 staging (21 loads issued back-to-back -> latency overlapped; the
// dynamic-loop variant serialized the loads and cost ~20 us in round 1). Tail block
// (48 rows) takes the slow path -- only 16 of 6304 blocks. Writes 24-bit key
// (0 = invalid).
__global__ __launch_bounds__(64) void k_score(const float* __restrict__ pred,
                                              u32* __restrict__ keys,
                                              int* __restrict__ clsArr) {
  __shared__ float sh[64 * ROWLEN];          // 21760 B -> 7 blocks/CU
  const int t = threadIdx.x;
  const int bi = blockIdx.x;                 // 0..393 within image
  const int img = blockIdx.y;                // 0..15
  const int r0 = bi * 64;
  const float4* src = (const float4*)(pred + ((size_t)img * NN + r0) * ROWLEN);
  float4* dst = (float4*)sh;
  if (r0 + 64 <= NN) {
    #pragma unroll
    for (int i = 0; i < 21; ++i) dst[t + 64 * i] = src[t + 64 * i];
    if (t < 16) dst[t + 64 * 21] = src[t + 64 * 21];
  } else {
    const int nf4 = (NN - r0) * ROWLEN / 4;  // 48*85/4 = 1020
    for (int i = t; i < nf4; i += 64) dst[i] = src[i];
  }
  __syncthreads();
  const int nrows = (r0 + 64 <= NN) ? 64 : (NN - r0);
  if (t < nrows) {
    const float* row = sh + t * ROWLEN;
    float obj = row[4];
    float v0 = -INFINITY, v1 = -INFINITY, v2 = -INFINITY, v3 = -INFINITY;
    int j0 = 0, j1 = 20, j2 = 40, j3 = 60;
    #pragma unroll
    for (int c = 0; c < 20; ++c) {
      float s0 = obj * row[5 + c];
      float s1 = obj * row[25 + c];
      float s2 = obj * row[45 + c];
      float s3 = obj * row[65 + c];
      if (s0 > v0) { v0 = s0; j0 = c; }
      if (s1 > v1) { v1 = s1; j1 = 20 + c; }
      if (s2 > v2) { v2 = s2; j2 = 40 + c; }
      if (s3 > v3) { v3 = s3; j3 = 60 + c; }
    }
    float v = v0; int j = j0;
    if (v1 > v) { v = v1; j = j1; }
    if (v2 > v) { v = v2; j = j2; }
    if (v3 > v) { v = v3; j = j3; }
    u32 key = (v > CONF_T) ? (f2key(v) - KBASE) : 0u;   // 24-bit, >= 1 when valid
    size_t r = (size_t)img * NN + r0 + t;
    keys[r] = key;
    clsArr[r] = j;
  }
}

// ---- bitonic helper ----
__device__ __forceinline__ void bt_apply(u64& e, u64 p, int m, int j, int k) {
  bool lower = ((m & j) == 0);
  bool dir = ((m & k) == 0);
  bool takeMax = (lower == dir);
  u64 mx = e > p ? e : p;
  u64 mn = e > p ? p : e;
  e = takeMax ? mx : mn;
}

// -------- K2: top-1024 via 24-bit rank radix select (3 passes) + hybrid bitonic -----
// Pass 1: per-wave hist[16][257] LDS atomics (verified). Passes 2/3: single hist1
// (few matching elements). Sort: fast path when cnt<=1024 (no ties at threshold ->
// e1 region all zero -> sort e0 only, skip k=2048 merge).
__global__ __launch_bounds__(1024, 4) void k_select(const float* __restrict__ pred,
                                                    const u32* __restrict__ keys,
                                                    const int* __restrict__ clsArr,
                                                    float* __restrict__ candScore,
                                                    float* __restrict__ candBox,
                                                    int* __restrict__ candCls) {
  __shared__ u32 hist[16][257];
  __shared__ u32 hist1[257];
  __shared__ u64 buf[2048];
  __shared__ u32 sh_sel, sh_rem, sh_cnt;
  const int b = blockIdx.x;
  const int tid = threadIdx.x;
  const int lane = tid & 63;
  const int wv = tid >> 6;
  const u32* kk = keys + (size_t)b * NN;
  u32* histflat = (u32*)hist;

  u32 rr[25];
  #pragma unroll
  for (int it = 0; it < 25; ++it) {
    int n0 = tid + it * 1024;
    rr[it] = (n0 < NN) ? kk[n0] : 0u;
  }

  // ---- pass 1: top byte, per-wave private histograms (no contention) ----
  for (int i = tid; i < 16 * 257; i += 1024) histflat[i] = 0;
  if (tid == 0) sh_cnt = 0;
  __syncthreads();
  #pragma unroll
  for (int it = 0; it < 25; ++it) {
    u32 r = rr[it];
    if (r != 0u) atomicAdd(&hist[wv][r >> 16], 1u);
  }
  __syncthreads();
  if (wv == 0) {
    u32 c0 = 0, c1 = 0, c2 = 0, c3 = 0;
    #pragma unroll
    for (int w = 0; w < 16; ++w) {
      c0 += hist[w][4 * lane + 0];
      c1 += hist[w][4 * lane + 1];
      c2 += hist[w][4 * lane + 2];
      c3 += hist[w][4 * lane + 3];
    }
    u32 tl = c0 + c1 + c2 + c3;
    u32 incl = tl;
    #pragma unroll
    for (int off = 1; off <= 32; off <<= 1) {
      u32 o = __shfl_down(incl, off, 64);
      if (lane + off < 64) incl += o;
    }
    u32 S0 = incl;
    u32 S1 = S0 - c0;
    u32 S2 = S1 - c1;
    u32 S3 = S2 - c2;
    u32 S4 = S3 - c3;
    u32 rem = KCAND;
    if (S0 >= rem && S1 < rem) { sh_sel = 4 * lane + 0; sh_rem = rem - S1; }
    if (S1 >= rem && S2 < rem) { sh_sel = 4 * lane + 1; sh_rem = rem - S2; }
    if (S2 >= rem && S3 < rem) { sh_sel = 4 * lane + 2; sh_rem = rem - S3; }
    if (S3 >= rem && S4 < rem) { sh_sel = 4 * lane + 3; sh_rem = rem - S4; }
  }
  __syncthreads();
  u32 prefix = (sh_sel << 16);
  u32 remaining = sh_rem;
  u32 himask = 0xFF0000u;
  __syncthreads();

  // ---- passes 2 and 3: only prefix-matching elements (~bucket-sized) do atomics ----
  #pragma unroll
  for (int pass = 1; pass < 3; ++pass) {
    const int shift = 16 - 8 * pass;
    if (tid < 256) hist1[tid] = 0u;
    __syncthreads();
    #pragma unroll
    for (int it = 0; it < 25; ++it) {
      u32 r = rr[it];
      if (r != 0u && (r & himask) == prefix)
        atomicAdd(&hist1[(r >> shift) & 255], 1u);
    }
    __syncthreads();
    if (wv == 0) {
      const int j4 = lane << 2;
      u32 c0 = hist1[j4 + 0], c1 = hist1[j4 + 1], c2 = hist1[j4 + 2], c3 = hist1[j4 + 3];
      u32 tl = c0 + c1 + c2 + c3;
      u32 incl = tl;
      #pragma unroll
      for (int off = 1; off <= 32; off <<= 1) {
        u32 o = __shfl_down(incl, off, 64);
        if (lane + off < 64) incl += o;
      }
      u32 S0 = incl;
      u32 S1 = S0 - c0;
      u32 S2 = S1 - c1;
      u32 S3 = S2 - c2;
      u32 S4 = S3 - c3;
      u32 rem = remaining;
      if (S0 >= rem && S1 < rem) { sh_sel = 4 * lane + 0; sh_rem = rem - S1; }
      if (S1 >= rem && S2 < rem) { sh_sel = 4 * lane + 1; sh_rem = rem - S2; }
      if (S2 >= rem && S3 < rem) { sh_sel = 4 * lane + 2; sh_rem = rem - S3; }
      if (S3 >= rem && S4 < rem) { sh_sel = 4 * lane + 3; sh_rem = rem - S4; }
    }
    __syncthreads();
    prefix |= (sh_sel << shift);
    remaining = sh_rem;
    himask |= (0xFFu << shift);
    __syncthreads();
  }
  const u32 T = prefix;   // exact 24-bit threshold, T >= 1

  // ---- exact-threshold compaction (order irrelevant: full sort follows) ----
  #pragma unroll
  for (int it = 0; it < 25; ++it) {
    int n0 = tid + it * 1024;
    u32 r = rr[it];
    bool match = (r >= T);             // r==0 (invalid/OOB) never matches, T>=1
    u64 bal = __ballot(match);
    if (bal) {
      int leader = __ffsll((unsigned long long)bal) - 1;
      u32 base = 0;
      u32 cnt = (u32)__popcll(bal);
      if (lane == leader) base = atomicAdd(&sh_cnt, cnt);
      base = __shfl(base, leader, 64);
      if (match) {
        u32 pos = base + (u32)__popcll(bal & ((1ull << lane) - 1ull));
        if (pos < 2048) buf[pos] = ((u64)r << 32) | (u32)(~(u32)n0);
      }
    }
  }
  __syncthreads();
  u32 c = sh_cnt; if (c > 2048) c = 2048;
  for (int t = tid; t < 2048; t += 1024) if (t >= (int)c) buf[t] = 0;
  __syncthreads();

  u64 e0 = buf[tid];
  if (c <= 1024) {
    // fast path: no ties at threshold -> buf[1024..2047] all zero; sort e0 only.
    #pragma unroll
    for (int k = 2; k <= 64; k <<= 1) {
      #pragma unroll
      for (int j = k >> 1; j > 0; j >>= 1) {
        u64 p0 = __shfl_xor(e0, j, 64);
        bt_apply(e0, p0, tid, j, k);
      }
    }
    for (int k = 128; k <= 1024; k <<= 1) {
      for (int j = k >> 1; j >= 64; j >>= 1) {
        buf[tid] = e0;
        __syncthreads();
        u64 p0 = buf[tid ^ j];
        bt_apply(e0, p0, tid, j, k);
        __syncthreads();
      }
      #pragma unroll
      for (int j = 32; j > 0; j >>= 1) {
        u64 p0 = __shfl_xor(e0, j, 64);
        bt_apply(e0, p0, tid, j, k);
      }
    }
  } else {
    // full 2048 path (tie at threshold) -- verified baseline
    u64 e1 = buf[tid + 1024];
    #pragma unroll
    for (int k = 2; k <= 64; k <<= 1) {
      #pragma unroll
      for (int j = k >> 1; j > 0; j >>= 1) {
        u64 p0 = __shfl_xor(e0, j, 64);
        u64 p1 = __shfl_xor(e1, j, 64);
        bt_apply(e0, p0, tid, j, k);
        bt_apply(e1, p1, tid + 1024, j, k);
      }
    }
    for (int k = 128; k <= 2048; k <<= 1) {
      int jstart = k >> 1;
      if (k == 2048) {
        u64 mx = e0 > e1 ? e0 : e1;
        u64 mn = e0 > e1 ? e1 : e0;
        e0 = mx; e1 = mn;
        jstart = 512;
      }
      for (int j = jstart; j >= 64; j >>= 1) {
        buf[tid] = e0; buf[tid + 1024] = e1;
        __syncthreads();
        u64 p0 = buf[tid ^ j];
        u64 p1 = buf[(tid ^ j) + 1024];
        bt_apply(e0, p0, tid, j, k);
        bt_apply(e1, p1, tid + 1024, j, k);
        __syncthreads();
      }
      #pragma unroll
      for (int j = 32; j > 0; j >>= 1) {
        u64 p0 = __shfl_xor(e0, j, 64);
        u64 p1 = __shfl_xor(e1, j, 64);
        bt_apply(e0, p0, tid, j, k);
        bt_apply(e1, p1, tid + 1024, j, k);
      }
    }
  }
  {
    u64 e = e0;
    u32 r = (u32)(e >> 32);
    u32 idx = ~(u32)e;
    if (idx >= NN) idx = 0;
    float sc = key2f(r + KBASE);
    size_t g = (size_t)b * KCAND + tid;
    candScore[g] = sc;
    const float* p = pred + ((size_t)b * NN + idx) * ROWLEN;
    float cx = p[0], cy = p[1], w = p[2], h = p[3];
    float4 bx;
    bx.x = cx - 0.5f * w;
    bx.y = cy - 0.5f * h;
    bx.z = cx + 0.5f * w;
    bx.w = cy + 0.5f * h;
    ((float4*)candBox)[g] = bx;
    candCls[g] = clsArr[(size_t)b * NN + idx];
  }
}

// ---------------- K3a: ballot-transpose IoU, LOWER WEDGE ONLY (rc <= cc) -----------
__global__ __launch_bounds__(64) void k_iou(const float* __restrict__ candBox,
                                            const int* __restrict__ candCls,
                                            u64* __restrict__ matT) {
  #pragma clang fp contract(off)
  __shared__ float4 sb[64];
  __shared__ float sa[64];
  const int rc = blockIdx.x;       // row chunk
  const int cc = blockIdx.y;       // col chunk
  const int b  = blockIdx.z;
  if (rc > cc) return;
  const int lane = threadIdx.x;
  {
    int rrow = rc * 64 + lane;
    float4 bx = ((const float4*)candBox)[(size_t)b * KCAND + rrow];
    float off = (float)candCls[(size_t)b * KCAND + rrow] * MAX_WH;
    float x1 = bx.x + off, y1 = bx.y + off, x2 = bx.z + off, y2 = bx.w + off;
    float4 sbv; sbv.x = x1; sbv.y = y1; sbv.z = x2; sbv.w = y2;
    sb[lane] = sbv;
    sa[lane] = (x2 - x1) * (y2 - y1);
  }
  int col = cc * 64 + lane;
  float4 cb = ((const float4*)candBox)[(size_t)b * KCAND + col];
  float coff = (float)candCls[(size_t)b * KCAND + col] * MAX_WH;
  float cx1 = cb.x + coff, cy1 = cb.y + coff, cx2 = cb.z + coff, cy2 = cb.w + coff;
  float car = (cx2 - cx1) * (cy2 - cy1);
  __syncthreads();
  u64 myw = 0;
  for (int r = 0; r < 64; ++r) {
    float4 rb = sb[r];
    float ra = sa[r];
    float ix1 = fmaxf(rb.x, cx1);
    float iy1 = fmaxf(rb.y, cy1);
    float ix2 = fminf(rb.z, cx2);
    float iy2 = fminf(rb.w, cy2);
    float dx = fmaxf(ix2 - ix1, 0.0f);
    float dy = fmaxf(iy2 - iy1, 0.0f);
    float inter = dx * dy;
    float den = ra + car;
    den = den - inter;
    den = den + 1e-9f;
    float iou = inter / den;
    u64 bal = __ballot(iou > IOU_T);
    if (lane == r) myw = bal;
  }
  matT[(((size_t)b * 16 + cc) << 10) + rc * 64 + lane] = myw;
}

// -------- K3b (fused scan + output): lower-triangle words in LDS, not registers -----
// Round-3 post-mortem: the tri[120]-in-registers design (~340 VGPR) sat on the
// regalloc cliff; an unrelated co-compiled edit tipped it into full spill
// (VGPR_Count=96, 216 us of scratch traffic). LDS version is structurally
// spill-proof: sTri = 120 pairs x 64 lanes x 8B = 61440 B (fits 64 KB block LDS),
// staged as 15 contiguous coalesced copies by all 4 waves; scan reads ds_read_b64
// (2-way bank aliasing = free). Register footprint ~150 VGPR.
#define TRIDX(c, cp) (((c) * ((c)-1)) / 2 + (cp))
__global__ __launch_bounds__(256, 1) void k_scan_out(const u64* __restrict__ matT,
                                                     const float* __restrict__ candScore,
                                                     const float* __restrict__ candBox,
                                                     const int* __restrict__ candCls,
                                                     float* __restrict__ out) {
  __shared__ u64 sTri[120 * 64];    // 61440 B
  __shared__ u64 sKeep[16];
  const int b = blockIdx.x;
  const int tid = threadIdx.x;
  const u64* Mb = matT + ((size_t)b << 14);

  // stage the lower wedge: for chunk c, words for cp<c are the contiguous run
  // Mb[(c<<10) .. (c<<10)+c*64). Unrolled, static trip counts -> batched loads.
  #pragma unroll
  for (int c = 1; c < 16; ++c) {
    const u64* src = Mb + ((size_t)c << 10);
    u64* dst = sTri + (size_t)TRIDX(c, 0) * 64;
    #pragma unroll
    for (int i = 0; i < c * 64; i += 256) {
      int idx = i + tid;
      if (idx < c * 64) dst[idx] = src[idx];
    }
  }
  __syncthreads();

  if (tid < 64) {
    const int lane = tid;
    u64 vw[16], dg[16], kcw[16];
    #pragma unroll
    for (int w = 0; w < 16; ++w) {
      float sc = candScore[(size_t)b * KCAND + w * 64 + lane];
      vw[w] = __ballot(sc > 0.0f);
    }
    #pragma unroll
    for (int c = 0; c < 16; ++c)
      dg[c] = Mb[((size_t)c << 10) + c * 64 + lane];

    #pragma unroll
    for (int c = 0; c < 16; ++c) {
      u64 acc = 0;
      #pragma unroll
      for (int cp = 0; cp < 15; ++cp) {
        if (cp < c) {
          if ((kcw[cp] >> lane) & 1ull) acc |= sTri[(size_t)TRIDX(c, cp) * 64 + lane];
        }
      }
      #pragma unroll
      for (int st = 1; st < 64; st <<= 1) acc |= __shfl_xor(acc, st, 64);
      u64 d = dg[c];
      u64 s = acc;
      u64 kc = 0;
      u64 vc = vw[c];
      #pragma unroll
      for (int g = 0; g < 8; ++g) {
        u64 dgp[8];
        #pragma unroll
        for (int j = 0; j < 8; ++j) dgp[j] = __shfl(d, g * 8 + j, 64);
        #pragma unroll
        for (int j = 0; j < 8; ++j) {
          int i = g * 8 + j;
          bool ok = !((s >> i) & 1ull) && ((vc >> i) & 1ull);
          if (ok) { s |= dgp[j]; kc |= (1ull << i); }
        }
      }
      kcw[c] = kc;    // lane-uniform
    }
    if (lane < 16) sKeep[lane] = kcw[lane];
  }
  __syncthreads();

  int total = 0;
  #pragma unroll
  for (int w = 0; w < 16; ++w) total += __popcll(sKeep[w]);
  int kept_eff = total < MAXDET ? total : MAXDET;
  float* outb = out + (size_t)b * MAXDET * 6;
  #pragma unroll
  for (int rr2 = 0; rr2 < 4; ++rr2) {
    const int t = tid + rr2 * 256;
    u64 word = sKeep[t >> 6];
    int bit = (int)((word >> (t & 63)) & 1ull);
    int rank = 0;
    for (int w = 0; w < (t >> 6); ++w) rank += __popcll(sKeep[w]);
    rank += __popcll(word & ((1ull << (t & 63)) - 1ull));
    if (bit && rank < MAXDET) {
      size_t g = (size_t)b * KCAND + t;
      float4 bx = ((const float4*)candBox)[g];
      float sc = candScore[g];
      float cf = (float)candCls[g];
      float* o = outb + (size_t)rank * 6;
      o[0] = bx.x; o[1] = bx.y; o[2] = bx.z; o[3] = bx.w; o[4] = sc; o[5] = cf;
    }
    if (t < MAXDET && t >= kept_eff) {
      float* o = outb + (size_t)t * 6;
      o[0] = 0.f; o[1] = 0.f; o[2] = 0.f; o[3] = 0.f; o[4] = 0.f; o[5] = 0.f;
    }
  }
}

extern "C" void kernel_launch(void* const* d_in, const int* in_sizes, int n_in,
                              void* d_out, int out_size, void* d_ws, size_t ws_size,
                              hipStream_t stream) {
  const float* pred = (const float*)d_in[0];
  float* out = (float*)d_out;
  char* ws = (char*)d_ws;
  size_t o = 0;
  u32*   keysW     = (u32*)  (ws + o); o += (size_t)BB * NN * 4;
  int*   clsArr    = (int*)  (ws + o); o += (size_t)BB * NN * 4;
  float* candScore = (float*)(ws + o); o += (size_t)BB * KCAND * 4;
  float* candBox   = (float*)(ws + o); o += (size_t)BB * KCAND * 16;
  int*   candCls   = (int*)  (ws + o); o += (size_t)BB * KCAND * 4;
  o = (o + 255) & ~(size_t)255;
  u64*   matT      = (u64*)  (ws + o); o += (size_t)BB * KCAND * 16 * 8;   // 2 MB

  k_score<<<dim3(NBLK, BB), 64, 0, stream>>>(pred, keysW, clsArr);
  k_select<<<BB, 1024, 0, stream>>>(pred, keysW, clsArr, candScore, candBox, candCls);
  k_iou<<<dim3(16, 16, BB), 64, 0, stream>>>(candBox, candCls, matT);
  k_scan_out<<<BB, 256, 0, stream>>>(matT, candScore, candBox, candCls, out);
}